// Round 1
// baseline (2462.582 us; speedup 1.0000x reference)
//
#include <hip/hip_runtime.h>
#include <stdint.h>

// R1: fused fp32 pipeline. K0 prep (fold BN2, transpose W/codewords to bf16, c2),
// K1 persistent fused conv+encode (feat tiles in LDS bf16, enc in regs, atomic flush),
// K2 BN1+mean+fc+sigmoid, K3 elementwise gate. GEMM is fp32 vector (437us floor);
// MFMA conversion planned for R2.

#define EPSV 1e-5f

constexpr int Bn = 8, Cn = 512, Kn = 32, Nn = 16384;
constexpr int TILE_N = 32, BKc = 32, NCHUNK = Cn / BKc;      // 16
constexpr int NBLK = 256, BLK_PER_B = NBLK / Bn;             // 32
constexpr int TILES_PER_BLK = (Nn / TILE_N) / BLK_PER_B;     // 16

// ws byte offsets
constexpr size_t OFF_ENC   = 0;              // 8*32*512 f32 = 524288 B (zeroed)
constexpr size_t OFF_AWSUM = 524288;         // 8*32 f32 = 1024 B (zeroed)
constexpr size_t OFF_GAMMA = 525312;         // 8*512 f32
constexpr size_t OFF_WT    = 541696;         // 512*512 bf16 [c][o]
constexpr size_t OFF_CWT   = 1065984;        // 512*32 bf16 [c][k]
constexpr size_t OFF_C2    = 1098752;        // 32 f32
constexpr size_t OFF_BNS   = 1098880;        // 512 f32
constexpr size_t OFF_BNB   = 1100928;        // 512 f32

__device__ __forceinline__ uint16_t f2bf(float f) {
  uint32_t u = __float_as_uint(f);
  u += 0x7fffu + ((u >> 16) & 1u);
  return (uint16_t)(u >> 16);
}
__device__ __forceinline__ float bflo(uint32_t d) { return __uint_as_float(d << 16); }
__device__ __forceinline__ float bfhi(uint32_t d) { return __uint_as_float(d & 0xffff0000u); }

__global__ void k0_prep(const float* __restrict__ conv_w, const float* __restrict__ codewords,
                        const float* __restrict__ g2, const float* __restrict__ b2,
                        const float* __restrict__ m2, const float* __restrict__ v2,
                        uint16_t* __restrict__ WT, uint16_t* __restrict__ cwT,
                        float* __restrict__ c2, float* __restrict__ bns, float* __restrict__ bnb)
{
  const int idx = blockIdx.x * blockDim.x + threadIdx.x;  // grid covers 262144
  if (idx < Cn * Cn) {
    const int o = idx >> 9, c = idx & 511;
    WT[c * 512 + o] = f2bf(conv_w[idx]);
  }
  if (idx < Kn * Cn) {
    const int k = idx >> 9, c = idx & 511;
    cwT[c * 32 + k] = f2bf(codewords[idx]);
  }
  if (idx < Cn) {
    const float s = g2[idx] * rsqrtf(v2[idx] + EPSV);
    bns[idx] = s;
    bnb[idx] = b2[idx] - m2[idx] * s;
  }
  if (idx < Kn) {
    float s = 0.f;
    for (int c = 0; c < Cn; ++c) { const float v = codewords[idx * 512 + c]; s = fmaf(v, v, s); }
    c2[idx] = s;
  }
}

__launch_bounds__(256, 1)
__global__ void k1_main(const float* __restrict__ x,
                        const uint16_t* __restrict__ WT,
                        const uint16_t* __restrict__ cwTg,
                        const float* __restrict__ bns, const float* __restrict__ bnb,
                        const float* __restrict__ c2g, const float* __restrict__ scaleg,
                        float* __restrict__ enc_raw, float* __restrict__ awsum)
{
  __shared__ uint16_t sW[BKc][512];       // 32 KB  staged W chunk (bf16, [c][o])
  __shared__ float    sX[BKc][TILE_N];    // 4 KB   staged X chunk (f32)
  __shared__ uint16_t sF[TILE_N][524];    // 33.5KB feat tile bf16, stride 524 (2-way free)
  __shared__ float    sAW[TILE_N][33];    // 4.2KB  logits -> softmax weights
  __shared__ float    sX2[TILE_N];
  __shared__ uint16_t sCW[512][32];       // 32 KB  codewords^T bf16
  __shared__ float    sScale[Kn];
  __shared__ float    sC2[Kn];

  const int t   = threadIdx.x;
  const int b   = blockIdx.x / BLK_PER_B;
  const int tb0 = blockIdx.x % BLK_PER_B;
  const int tx  = t & 3;     // GEMM n-group (8 n each)
  const int ty  = t >> 2;    // GEMM o-group (8 o each)
  const int lk  = t & 31;    // E1: n   | E3/flush: k
  const int lg  = t >> 5;    // E1: k-quad group | E3/flush: c-block of 64

  // stage codewords^T + scale + c2 (lane-interleaved, conflict-free)
  {
    const uint4* src = (const uint4*)cwTg;
    uint4* dst = (uint4*)&sCW[0][0];
#pragma unroll
    for (int u = 0; u < 8; ++u) dst[u * 256 + t] = src[u * 256 + t];
    if (t < Kn) { sScale[t] = scaleg[t]; sC2[t] = c2g[t]; }
  }

  // folded BN2 params for this thread's 8 output channels
  float bsv[8], bbv[8];
  {
    const float4* s4 = (const float4*)(bns + ty * 8);
    const float4* b4 = (const float4*)(bnb + ty * 8);
    const float4 a0 = s4[0], a1 = s4[1], c0 = b4[0], c1 = b4[1];
    bsv[0]=a0.x; bsv[1]=a0.y; bsv[2]=a0.z; bsv[3]=a0.w;
    bsv[4]=a1.x; bsv[5]=a1.y; bsv[6]=a1.z; bsv[7]=a1.w;
    bbv[0]=c0.x; bbv[1]=c0.y; bbv[2]=c0.z; bbv[3]=c0.w;
    bbv[4]=c1.x; bbv[5]=c1.y; bbv[6]=c1.z; bbv[7]=c1.w;
  }

  float enc[64];
#pragma unroll
  for (int u = 0; u < 64; ++u) enc[u] = 0.f;
  float awacc = 0.f;

  __syncthreads();

  for (int j = 0; j < TILES_PER_BLK; ++j) {
    const int n0 = (tb0 + j * BLK_PER_B) * TILE_N;

    // prefetch chunk 0 into regs
    uint4 wreg[8];
    uint4 xreg;
    {
      const uint4* wsrc = (const uint4*)WT;
#pragma unroll
      for (int u = 0; u < 8; ++u) wreg[u] = wsrc[u * 256 + t];
      xreg = *(const uint4*)(x + (size_t)(b * Cn + (t >> 3)) * Nn + n0 + (t & 7) * 4);
    }

    float acc[8][8];
#pragma unroll
    for (int oi = 0; oi < 8; ++oi)
#pragma unroll
      for (int ni = 0; ni < 8; ++ni) acc[oi][ni] = 0.f;

    for (int cc = 0; cc < NCHUNK; ++cc) {
      __syncthreads();  // prior readers of sW/sX done
      {
        uint4* wdst = (uint4*)&sW[0][0];
#pragma unroll
        for (int u = 0; u < 8; ++u) wdst[u * 256 + t] = wreg[u];
        ((uint4*)&sX[0][0])[t] = xreg;
      }
      __syncthreads();  // chunk cc visible
      if (cc + 1 < NCHUNK) {
        const uint4* wsrc = (const uint4*)(WT + (size_t)(cc + 1) * BKc * 512);
#pragma unroll
        for (int u = 0; u < 8; ++u) wreg[u] = wsrc[u * 256 + t];
        xreg = *(const uint4*)(x + (size_t)(b * Cn + (cc + 1) * BKc + (t >> 3)) * Nn + n0 + (t & 7) * 4);
      }
#pragma unroll 8
      for (int c = 0; c < BKc; ++c) {
        const uint4 a4 = *(const uint4*)&sW[c][ty * 8];
        float av[8];
        av[0] = bflo(a4.x); av[1] = bfhi(a4.x);
        av[2] = bflo(a4.y); av[3] = bfhi(a4.y);
        av[4] = bflo(a4.z); av[5] = bfhi(a4.z);
        av[6] = bflo(a4.w); av[7] = bfhi(a4.w);
        const float4 b0 = *(const float4*)&sX[c][tx * 8];
        const float4 b1 = *(const float4*)&sX[c][tx * 8 + 4];
        const float bv[8] = {b0.x, b0.y, b0.z, b0.w, b1.x, b1.y, b1.z, b1.w};
#pragma unroll
        for (int oi = 0; oi < 8; ++oi)
#pragma unroll
          for (int ni = 0; ni < 8; ++ni)
            acc[oi][ni] = fmaf(av[oi], bv[ni], acc[oi][ni]);
      }
    }

    // epilogue: BN2 + ReLU + bf16 pack -> sF[n][o]
#pragma unroll
    for (int ni = 0; ni < 8; ++ni) {
      const int n = tx * 8 + ni;
      uint32_t dw[4];
#pragma unroll
      for (int u = 0; u < 4; ++u) {
        const float v0 = fmaxf(fmaf(acc[2*u+0][ni], bsv[2*u+0], bbv[2*u+0]), 0.f);
        const float v1 = fmaxf(fmaf(acc[2*u+1][ni], bsv[2*u+1], bbv[2*u+1]), 0.f);
        dw[u] = (uint32_t)f2bf(v0) | ((uint32_t)f2bf(v1) << 16);
      }
      *(uint2*)&sF[n][ty * 8]     = make_uint2(dw[0], dw[1]);
      *(uint2*)&sF[n][ty * 8 + 4] = make_uint2(dw[2], dw[3]);
    }
    __syncthreads();

    // E1: xc (4 codes per thread) + x2 over C=512
    float xc0 = 0.f, xc1 = 0.f, xc2 = 0.f, xc3 = 0.f, x2 = 0.f;
    const int k4 = lg * 4;
#pragma unroll 2
    for (int c8 = 0; c8 < 64; ++c8) {
      const uint2 fa = *(const uint2*)&sF[lk][c8 * 8];
      const uint2 fb = *(const uint2*)&sF[lk][c8 * 8 + 4];
      float fv[8];
      fv[0] = bflo(fa.x); fv[1] = bfhi(fa.x); fv[2] = bflo(fa.y); fv[3] = bfhi(fa.y);
      fv[4] = bflo(fb.x); fv[5] = bfhi(fb.x); fv[6] = bflo(fb.y); fv[7] = bfhi(fb.y);
#pragma unroll
      for (int cj = 0; cj < 8; ++cj) {
        const int c = c8 * 8 + cj;
        x2 = fmaf(fv[cj], fv[cj], x2);
        const uint2 cw2 = *(const uint2*)&sCW[c][k4];
        xc0 = fmaf(fv[cj], bflo(cw2.x), xc0);
        xc1 = fmaf(fv[cj], bfhi(cw2.x), xc1);
        xc2 = fmaf(fv[cj], bflo(cw2.y), xc2);
        xc3 = fmaf(fv[cj], bfhi(cw2.y), xc3);
      }
    }
    if (lg == 0) sX2[lk] = x2;
    __syncthreads();
    {
      const float x2v = sX2[lk];
      sAW[lk][k4 + 0] = sScale[k4 + 0] * (x2v - 2.f * xc0 + sC2[k4 + 0]);
      sAW[lk][k4 + 1] = sScale[k4 + 1] * (x2v - 2.f * xc1 + sC2[k4 + 1]);
      sAW[lk][k4 + 2] = sScale[k4 + 2] * (x2v - 2.f * xc2 + sC2[k4 + 2]);
      sAW[lk][k4 + 3] = sScale[k4 + 3] * (x2v - 2.f * xc3 + sC2[k4 + 3]);
    }
    __syncthreads();
    // E2: softmax over K=32 per position
    if (t < TILE_N) {
      float m = -1e30f;
#pragma unroll
      for (int k = 0; k < Kn; ++k) m = fmaxf(m, sAW[t][k]);
      float s = 0.f;
#pragma unroll
      for (int k = 0; k < Kn; ++k) { const float e = __expf(sAW[t][k] - m); sAW[t][k] = e; s += e; }
      const float inv = 1.f / s;
#pragma unroll
      for (int k = 0; k < Kn; ++k) sAW[t][k] *= inv;
    }
    __syncthreads();

    // E3: enc[k][c] += sum_n aw[n][k] * feat[n][c]
    for (int n = 0; n < TILE_N; ++n) {
      const float a = sAW[n][lk];
      if (lg == 0) awacc += a;
#pragma unroll
      for (int u = 0; u < 8; ++u) {
        const uint2 fa = *(const uint2*)&sF[n][lg * 64 + u * 8];
        const uint2 fb = *(const uint2*)&sF[n][lg * 64 + u * 8 + 4];
        enc[u*8+0] = fmaf(a, bflo(fa.x), enc[u*8+0]);
        enc[u*8+1] = fmaf(a, bfhi(fa.x), enc[u*8+1]);
        enc[u*8+2] = fmaf(a, bflo(fa.y), enc[u*8+2]);
        enc[u*8+3] = fmaf(a, bfhi(fa.y), enc[u*8+3]);
        enc[u*8+4] = fmaf(a, bflo(fb.x), enc[u*8+4]);
        enc[u*8+5] = fmaf(a, bfhi(fb.x), enc[u*8+5]);
        enc[u*8+6] = fmaf(a, bflo(fb.y), enc[u*8+6]);
        enc[u*8+7] = fmaf(a, bfhi(fb.y), enc[u*8+7]);
      }
    }
    __syncthreads();
  }

  // flush partial aggregation
  float* dst = enc_raw + (size_t)(b * Kn + lk) * Cn + lg * 64;
#pragma unroll
  for (int u = 0; u < 64; ++u) atomicAdd(dst + u, enc[u]);
  if (lg == 0) atomicAdd(awsum + b * Kn + lk, awacc);
}

__global__ void k2_post(const float* __restrict__ enc_raw, const float* __restrict__ awsum,
                        const float* __restrict__ codewords,
                        const float* __restrict__ g1, const float* __restrict__ b1,
                        const float* __restrict__ m1, const float* __restrict__ v1,
                        const float* __restrict__ fc_w, const float* __restrict__ fc_b,
                        float* __restrict__ ef_out, float* __restrict__ gamma)
{
  __shared__ float efs[Cn];
  const int b = blockIdx.x, c = threadIdx.x;
  float s = 0.f;
#pragma unroll 4
  for (int k = 0; k < Kn; ++k) {
    const float aws = awsum[b * Kn + k];
    float e = enc_raw[(size_t)(b * Kn + k) * Cn + c] - aws * codewords[k * Cn + c];
    const float inv = rsqrtf(v1[k] + EPSV);
    e = (e - m1[k]) * (inv * g1[k]) + b1[k];
    s += fmaxf(e, 0.f);
  }
  s *= (1.f / 32.f);
  efs[c] = s;
  ef_out[b * Cn + c] = s;
  __syncthreads();
  const float4* w4 = (const float4*)(fc_w + (size_t)c * Cn);
  const float4* e4 = (const float4*)efs;
  float z = 0.f;
#pragma unroll 8
  for (int i = 0; i < Cn / 4; ++i) {
    const float4 w = w4[i], e = e4[i];
    z = fmaf(w.x, e.x, z); z = fmaf(w.y, e.y, z);
    z = fmaf(w.z, e.z, z); z = fmaf(w.w, e.w, z);
  }
  z += fc_b[c];
  gamma[b * Cn + c] = 1.f / (1.f + __expf(-z));
}

__global__ void k3_out(const float* __restrict__ x, const float* __restrict__ gamma,
                       float* __restrict__ out)
{
  const float4* x4 = (const float4*)x;
  float4* o4 = (float4*)out;
  int i = blockIdx.x * blockDim.x + threadIdx.x;  // grid 8192*256 = 2^21 threads
#pragma unroll
  for (int r = 0; r < 8; ++r, i += 2097152) {
    const int bb = i >> 21;
    const int cc = (i >> 12) & 511;
    const float g = 1.f + gamma[bb * 512 + cc];
    float4 v = x4[i];
    v.x = fmaxf(v.x * g, 0.f);
    v.y = fmaxf(v.y * g, 0.f);
    v.z = fmaxf(v.z * g, 0.f);
    v.w = fmaxf(v.w * g, 0.f);
    o4[i] = v;
  }
}

extern "C" void kernel_launch(void* const* d_in, const int* in_sizes, int n_in,
                              void* d_out, int out_size, void* d_ws, size_t ws_size,
                              hipStream_t stream) {
  const float* x      = (const float*)d_in[0];
  const float* conv_w = (const float*)d_in[1];
  const float* bn2g   = (const float*)d_in[2];
  const float* bn2b   = (const float*)d_in[3];
  const float* bn2m   = (const float*)d_in[4];
  const float* bn2v   = (const float*)d_in[5];
  const float* codew  = (const float*)d_in[6];
  const float* scale  = (const float*)d_in[7];
  const float* bn1g   = (const float*)d_in[8];
  const float* bn1b   = (const float*)d_in[9];
  const float* bn1m   = (const float*)d_in[10];
  const float* bn1v   = (const float*)d_in[11];
  const float* fc_w   = (const float*)d_in[12];
  const float* fc_b   = (const float*)d_in[13];

  char* ws = (char*)d_ws;
  float*    enc_raw = (float*)(ws + OFF_ENC);
  float*    awsum   = (float*)(ws + OFF_AWSUM);
  float*    gamma   = (float*)(ws + OFF_GAMMA);
  uint16_t* WT      = (uint16_t*)(ws + OFF_WT);
  uint16_t* cwT     = (uint16_t*)(ws + OFF_CWT);
  float*    c2      = (float*)(ws + OFF_C2);
  float*    bns     = (float*)(ws + OFF_BNS);
  float*    bnb     = (float*)(ws + OFF_BNB);

  hipMemsetAsync(ws, 0, OFF_GAMMA, stream);  // zero enc_raw + awsum
  k0_prep<<<1024, 256, 0, stream>>>(conv_w, codew, bn2g, bn2b, bn2m, bn2v,
                                    WT, cwT, c2, bns, bnb);
  k1_main<<<NBLK, 256, 0, stream>>>(x, WT, cwT, bns, bnb, c2, scale, enc_raw, awsum);
  k2_post<<<Bn, Cn, 0, stream>>>(enc_raw, awsum, codew, bn1g, bn1b, bn1m, bn1v,
                                 fc_w, fc_b, (float*)d_out, gamma);
  k3_out<<<8192, 256, 0, stream>>>(x, gamma, (float*)d_out + Bn * Cn);
}

// Round 2
// 1098.229 us; speedup vs baseline: 2.2423x; 2.2423x over previous
//
#include <hip/hip_runtime.h>
#include <stdint.h>

// R2: conv GEMM + soft-assign on MFMA (16x16x32 bf16). W read global->reg
// (no LDS staging: zero cross-wave W reuse). X transposed in-LDS per chunk.
// E3 aggregation still VALU (R3: MFMA via [c][n] feat copy).

#define EPSV 1e-5f

constexpr int Bn = 8, Cn = 512, Kn = 32, Nn = 16384;
constexpr int TILE_N = 64;
constexpr int NBLK = 256, BLK_PER_B = NBLK / Bn;             // 32
constexpr int TILES_PER_BLK = (Nn / TILE_N) / BLK_PER_B;     // 8

// ws byte offsets
constexpr size_t OFF_ENC   = 0;              // 8*32*512 f32 = 524288 (zeroed)
constexpr size_t OFF_AWSUM = 524288;         // 8*32 f32 (zeroed)
constexpr size_t OFF_GAMMA = 525312;         // 8*512 f32
constexpr size_t OFF_WT2   = 541696;         // 16 chunks * 512 o * 32 c bf16 = 524288
constexpr size_t OFF_CWB   = 1065984;        // 32*512 bf16 = 32768
constexpr size_t OFF_C2    = 1098752;        // 32 f32
constexpr size_t OFF_BNS   = 1098880;        // 512 f32
constexpr size_t OFF_BNB   = 1100928;        // 512 f32

typedef float f32x4 __attribute__((ext_vector_type(4)));
typedef __bf16 bf16x8 __attribute__((ext_vector_type(8)));
union U4B8 { uint4 u; bf16x8 b; };

__device__ __forceinline__ uint32_t f2bf(float f) {
  uint32_t u = __float_as_uint(f);
  u += 0x7fffu + ((u >> 16) & 1u);
  return u >> 16;
}
__device__ __forceinline__ float bflo(uint32_t d) { return __uint_as_float(d << 16); }
__device__ __forceinline__ float bfhi(uint32_t d) { return __uint_as_float(d & 0xffff0000u); }

__global__ void k0_prep(const float* __restrict__ conv_w, const float* __restrict__ codewords,
                        const float* __restrict__ g2, const float* __restrict__ b2,
                        const float* __restrict__ m2, const float* __restrict__ v2,
                        uint16_t* __restrict__ WT2, uint16_t* __restrict__ cwb,
                        float* __restrict__ c2, float* __restrict__ bns, float* __restrict__ bnb)
{
  const int idx = blockIdx.x * blockDim.x + threadIdx.x;  // 1024*256 = 262144
  if (idx < Cn * Cn) {
    const int o = idx >> 9, c = idx & 511;
    const int cc = c >> 5, cl = c & 31;
    WT2[((size_t)cc * 512 + o) * 32 + cl] = (uint16_t)f2bf(conv_w[idx]);
  }
  if (idx < Kn * Cn) cwb[idx] = (uint16_t)f2bf(codewords[idx]);
  if (idx < Cn) {
    const float s = g2[idx] * rsqrtf(v2[idx] + EPSV);
    bns[idx] = s;
    bnb[idx] = b2[idx] - m2[idx] * s;
  }
  if (idx < Kn) {
    float s = 0.f;
    for (int c = 0; c < Cn; ++c) { const float v = codewords[idx * 512 + c]; s = fmaf(v, v, s); }
    c2[idx] = s;
  }
}

__launch_bounds__(512, 2)
__global__ void k1_main(const float* __restrict__ x,
                        const uint16_t* __restrict__ WT2,
                        const uint16_t* __restrict__ cwb,
                        const float* __restrict__ bns, const float* __restrict__ bnb,
                        const float* __restrict__ c2g, const float* __restrict__ scaleg,
                        float* __restrict__ enc_raw, float* __restrict__ awsum)
{
  __shared__ __align__(16) float    sXstage[32][65];  // 8.3 KB  f32 chunk [c][n], stride 65 (bank-spread)
  __shared__ __align__(16) uint16_t sXT[64][40];      // 5 KB    bf16 [n][c32], row 80B (b128-aligned)
  __shared__ __align__(16) uint16_t sF[64][520];      // 66.6 KB feat bf16 [n][c], row 1040B
  __shared__ __align__(16) uint16_t sCW[32][520];     // 33.3 KB codewords bf16 [k][c]
  __shared__ __align__(16) float    sAW[64][33];      // 8.4 KB  xc -> aw
  __shared__ float sX2[64];
  __shared__ float sBNs[512], sBNb[512];
  __shared__ float sScale[Kn], sC2[Kn];

  const int t    = threadIdx.x;
  const int lane = t & 63, w = t >> 6;       // 8 waves
  const int col  = lane & 15, quad = lane >> 4;
  const int b    = blockIdx.x / BLK_PER_B;
  const int tb0  = blockIdx.x % BLK_PER_B;

  // one-time staging: codewords (padded rows), BN params, scale/c2
  {
    const int row = t >> 4, seg = t & 15;    // 32 rows x 16 segs of 64B
    const uint4* src = (const uint4*)(cwb + row * 512 + seg * 32);
    uint4* dst = (uint4*)&sCW[row][seg * 32];
#pragma unroll
    for (int u = 0; u < 4; ++u) dst[u] = src[u];
    sBNs[t] = bns[t];
    sBNb[t] = bnb[t];
    if (t < Kn) { sScale[t] = scaleg[t]; sC2[t] = c2g[t]; }
  }

  float enc[32];
#pragma unroll
  for (int u = 0; u < 32; ++u) enc[u] = 0.f;
  float awacc = 0.f;
  const int k_e3 = t & 31, cg = t >> 5;      // E3: 32 k x 16 c-groups of 32

  for (int j = 0; j < TILES_PER_BLK; ++j) {
    const int n0 = (tb0 + j * BLK_PER_B) * TILE_N;

    f32x4 acc[4][4];
#pragma unroll
    for (int ot = 0; ot < 4; ++ot)
#pragma unroll
      for (int nt = 0; nt < 4; ++nt) acc[ot][nt] = (f32x4){0.f, 0.f, 0.f, 0.f};

    // prefetch chunk 0: A frags (global->reg) + x rows
    uint4 areg[2][4];
    float4 xreg;
    {
      const uint16_t* wp = WT2 + (w * 64 + col) * 32 + quad * 8;
#pragma unroll
      for (int ot = 0; ot < 4; ++ot) areg[0][ot] = *(const uint4*)(wp + ot * 512);
      xreg = *(const float4*)(x + ((size_t)(b * Cn) + (t >> 4)) * Nn + n0 + (t & 15) * 4);
    }

#pragma unroll
    for (int cc = 0; cc < 16; ++cc) {
      const int cur = cc & 1, nxt = cur ^ 1;
      __syncthreads();                                   // B1: protect sXstage/sXT
      {
        const int c_l = t >> 4, n4 = (t & 15) * 4;
        sXstage[c_l][n4 + 0] = xreg.x;
        sXstage[c_l][n4 + 1] = xreg.y;
        sXstage[c_l][n4 + 2] = xreg.z;
        sXstage[c_l][n4 + 3] = xreg.w;
      }
      __syncthreads();                                   // B2: sXstage visible
      {
        const int n = t >> 3, c4 = (t & 7) * 4;
        const float v0 = sXstage[c4 + 0][n], v1 = sXstage[c4 + 1][n];
        const float v2 = sXstage[c4 + 2][n], v3 = sXstage[c4 + 3][n];
        *(uint2*)&sXT[n][c4] = make_uint2(f2bf(v0) | (f2bf(v1) << 16),
                                          f2bf(v2) | (f2bf(v3) << 16));
      }
      if (cc + 1 < 16)
        xreg = *(const float4*)(x + ((size_t)(b * Cn) + (cc + 1) * 32 + (t >> 4)) * Nn + n0 + (t & 15) * 4);
      __syncthreads();                                   // B3: sXT visible
      if (cc + 1 < 16) {
        const uint16_t* wp = WT2 + (size_t)(cc + 1) * 16384 + (w * 64 + col) * 32 + quad * 8;
#pragma unroll
        for (int ot = 0; ot < 4; ++ot) areg[nxt][ot] = *(const uint4*)(wp + ot * 512);
      }
      U4B8 bfr[4];
#pragma unroll
      for (int nt = 0; nt < 4; ++nt) bfr[nt].u = *(const uint4*)&sXT[nt * 16 + col][quad * 8];
#pragma unroll
      for (int ot = 0; ot < 4; ++ot) {
        U4B8 a; a.u = areg[cur][ot];
#pragma unroll
        for (int nt = 0; nt < 4; ++nt)
          acc[ot][nt] = __builtin_amdgcn_mfma_f32_16x16x32_bf16(a.b, bfr[nt].b, acc[ot][nt], 0, 0, 0);
      }
    }

    // epilogue: BN2 + ReLU + bf16 pack -> sF[n][o]  (r-dim = 4 consecutive o -> b64)
#pragma unroll
    for (int ot = 0; ot < 4; ++ot) {
      const int ob = w * 64 + ot * 16 + quad * 4;
      const float4 s4 = *(const float4*)&sBNs[ob];
      const float4 b4 = *(const float4*)&sBNb[ob];
#pragma unroll
      for (int nt = 0; nt < 4; ++nt) {
        const f32x4 a = acc[ot][nt];
        const float r0 = fmaxf(fmaf(a[0], s4.x, b4.x), 0.f);
        const float r1 = fmaxf(fmaf(a[1], s4.y, b4.y), 0.f);
        const float r2 = fmaxf(fmaf(a[2], s4.z, b4.z), 0.f);
        const float r3 = fmaxf(fmaf(a[3], s4.w, b4.w), 0.f);
        *(uint2*)&sF[nt * 16 + col][ob] = make_uint2(f2bf(r0) | (f2bf(r1) << 16),
                                                     f2bf(r2) | (f2bf(r3) << 16));
      }
    }
    __syncthreads();                                     // B_e1: sF visible

    // x2: thread (n = t>>3, 64-c slice)
    {
      const int n = t >> 3, cb = (t & 7) * 64;
      float s = 0.f;
#pragma unroll
      for (int u = 0; u < 8; ++u) {
        const uint4 d = *(const uint4*)&sF[n][cb + u * 8];
        s = fmaf(bflo(d.x), bflo(d.x), s); s = fmaf(bfhi(d.x), bfhi(d.x), s);
        s = fmaf(bflo(d.y), bflo(d.y), s); s = fmaf(bfhi(d.y), bfhi(d.y), s);
        s = fmaf(bflo(d.z), bflo(d.z), s); s = fmaf(bfhi(d.z), bfhi(d.z), s);
        s = fmaf(bflo(d.w), bflo(d.w), s); s = fmaf(bfhi(d.w), bfhi(d.w), s);
      }
      s += __shfl_xor(s, 1); s += __shfl_xor(s, 2); s += __shfl_xor(s, 4);
      if ((t & 7) == 0) sX2[n] = s;
    }

    // E1: xc via MFMA — wave w handles tile (kt = w&1, nt = w>>1)
    {
      const int kt = w & 1, ntl = w >> 1;
      f32x4 xca = (f32x4){0.f, 0.f, 0.f, 0.f};
#pragma unroll
      for (int ks = 0; ks < 16; ++ks) {
        U4B8 af, bf;
        af.u = *(const uint4*)&sCW[kt * 16 + col][ks * 32 + quad * 8];
        bf.u = *(const uint4*)&sF[ntl * 16 + col][ks * 32 + quad * 8];
        xca = __builtin_amdgcn_mfma_f32_16x16x32_bf16(af.b, bf.b, xca, 0, 0, 0);
      }
#pragma unroll
      for (int r = 0; r < 4; ++r)
        sAW[ntl * 16 + col][kt * 16 + quad * 4 + r] = xca[r];
    }
    __syncthreads();                                     // B_e2: xc + x2 visible

    // softmax over K=32 per position (threads 0..63), logits built in-place
    if (t < 64) {
      const float x2v = sX2[t];
      float m = -1e30f;
#pragma unroll
      for (int k = 0; k < Kn; ++k) {
        const float l = sScale[k] * (x2v - 2.f * sAW[t][k] + sC2[k]);
        sAW[t][k] = l;
        m = fmaxf(m, l);
      }
      float s = 0.f;
#pragma unroll
      for (int k = 0; k < Kn; ++k) { const float e = __expf(sAW[t][k] - m); sAW[t][k] = e; s += e; }
      const float inv = 1.f / s;
#pragma unroll
      for (int k = 0; k < Kn; ++k) sAW[t][k] *= inv;
    }
    __syncthreads();                                     // B_e3: aw visible

    // E3: enc[k][c] += sum_n aw[n][k] * feat[n][c]   (VALU; R3: MFMA)
#pragma unroll 2
    for (int n = 0; n < TILE_N; ++n) {
      const float a = sAW[n][k_e3];
      if (cg == 0) awacc += a;
      const uint16_t* fp = &sF[n][cg * 32];
#pragma unroll
      for (int u = 0; u < 4; ++u) {
        const uint4 d = *(const uint4*)(fp + u * 8);
        enc[u*8+0] = fmaf(a, bflo(d.x), enc[u*8+0]);
        enc[u*8+1] = fmaf(a, bfhi(d.x), enc[u*8+1]);
        enc[u*8+2] = fmaf(a, bflo(d.y), enc[u*8+2]);
        enc[u*8+3] = fmaf(a, bfhi(d.y), enc[u*8+3]);
        enc[u*8+4] = fmaf(a, bflo(d.z), enc[u*8+4]);
        enc[u*8+5] = fmaf(a, bfhi(d.z), enc[u*8+5]);
        enc[u*8+6] = fmaf(a, bflo(d.w), enc[u*8+6]);
        enc[u*8+7] = fmaf(a, bfhi(d.w), enc[u*8+7]);
      }
    }
  }

  // flush
  float* dst = enc_raw + ((size_t)b * Kn + k_e3) * Cn + cg * 32;
#pragma unroll
  for (int u = 0; u < 32; ++u) atomicAdd(dst + u, enc[u]);
  if (cg == 0) atomicAdd(awsum + b * Kn + k_e3, awacc);
}

__global__ void k2_post(const float* __restrict__ enc_raw, const float* __restrict__ awsum,
                        const float* __restrict__ codewords,
                        const float* __restrict__ g1, const float* __restrict__ b1,
                        const float* __restrict__ m1, const float* __restrict__ v1,
                        const float* __restrict__ fc_w, const float* __restrict__ fc_b,
                        float* __restrict__ ef_out, float* __restrict__ gamma)
{
  __shared__ float efs[Cn];
  const int b = blockIdx.x, c = threadIdx.x;
  float s = 0.f;
#pragma unroll 4
  for (int k = 0; k < Kn; ++k) {
    const float aws = awsum[b * Kn + k];
    float e = enc_raw[((size_t)b * Kn + k) * Cn + c] - aws * codewords[k * Cn + c];
    const float inv = rsqrtf(v1[k] + EPSV);
    e = (e - m1[k]) * (inv * g1[k]) + b1[k];
    s += fmaxf(e, 0.f);
  }
  s *= (1.f / 32.f);
  efs[c] = s;
  ef_out[b * Cn + c] = s;
  __syncthreads();
  const float4* w4 = (const float4*)(fc_w + (size_t)c * Cn);
  const float4* e4 = (const float4*)efs;
  float z = 0.f;
#pragma unroll 8
  for (int i = 0; i < Cn / 4; ++i) {
    const float4 w = w4[i], e = e4[i];
    z = fmaf(w.x, e.x, z); z = fmaf(w.y, e.y, z);
    z = fmaf(w.z, e.z, z); z = fmaf(w.w, e.w, z);
  }
  z += fc_b[c];
  gamma[b * Cn + c] = 1.f / (1.f + __expf(-z));
}

__global__ void k3_out(const float* __restrict__ x, const float* __restrict__ gamma,
                       float* __restrict__ out)
{
  const float4* x4 = (const float4*)x;
  float4* o4 = (float4*)out;
  int i = blockIdx.x * blockDim.x + threadIdx.x;
#pragma unroll
  for (int r = 0; r < 8; ++r, i += 2097152) {
    const int bb = i >> 21;
    const int cc = (i >> 12) & 511;
    const float g = 1.f + gamma[bb * 512 + cc];
    float4 v = x4[i];
    v.x = fmaxf(v.x * g, 0.f);
    v.y = fmaxf(v.y * g, 0.f);
    v.z = fmaxf(v.z * g, 0.f);
    v.w = fmaxf(v.w * g, 0.f);
    o4[i] = v;
  }
}

extern "C" void kernel_launch(void* const* d_in, const int* in_sizes, int n_in,
                              void* d_out, int out_size, void* d_ws, size_t ws_size,
                              hipStream_t stream) {
  const float* x      = (const float*)d_in[0];
  const float* conv_w = (const float*)d_in[1];
  const float* bn2g   = (const float*)d_in[2];
  const float* bn2b   = (const float*)d_in[3];
  const float* bn2m   = (const float*)d_in[4];
  const float* bn2v   = (const float*)d_in[5];
  const float* codew  = (const float*)d_in[6];
  const float* scale  = (const float*)d_in[7];
  const float* bn1g   = (const float*)d_in[8];
  const float* bn1b   = (const float*)d_in[9];
  const float* bn1m   = (const float*)d_in[10];
  const float* bn1v   = (const float*)d_in[11];
  const float* fc_w   = (const float*)d_in[12];
  const float* fc_b   = (const float*)d_in[13];

  char* ws = (char*)d_ws;
  float*    enc_raw = (float*)(ws + OFF_ENC);
  float*    awsum   = (float*)(ws + OFF_AWSUM);
  float*    gamma   = (float*)(ws + OFF_GAMMA);
  uint16_t* WT2     = (uint16_t*)(ws + OFF_WT2);
  uint16_t* cwb     = (uint16_t*)(ws + OFF_CWB);
  float*    c2      = (float*)(ws + OFF_C2);
  float*    bns     = (float*)(ws + OFF_BNS);
  float*    bnb     = (float*)(ws + OFF_BNB);

  hipMemsetAsync(ws, 0, OFF_GAMMA, stream);  // zero enc_raw + awsum
  k0_prep<<<1024, 256, 0, stream>>>(conv_w, codew, bn2g, bn2b, bn2m, bn2v,
                                    WT2, cwb, c2, bns, bnb);
  k1_main<<<NBLK, 512, 0, stream>>>(x, WT2, cwb, bns, bnb, c2, scale, enc_raw, awsum);
  k2_post<<<Bn, Cn, 0, stream>>>(enc_raw, awsum, codew, bn1g, bn1b, bn1m, bn1v,
                                 fc_w, fc_b, (float*)d_out, gamma);
  k3_out<<<8192, 256, 0, stream>>>(x, gamma, (float*)d_out + Bn * Cn);
}